// Round 1
// baseline (435.011 us; speedup 1.0000x reference)
//
#include <hip/hip_runtime.h>
#include <stdint.h>

#define SEQS 64
#define QL 4
#define KL 2048
#define NH 32
#define KVH 4
#define GRP 8
#define DN 128
#define DR 64
#define BS 16

typedef __attribute__((ext_vector_type(4))) float f32x4;
typedef __attribute__((ext_vector_type(8))) short s16x8;

#define VT_STRIDE 40   // shorts per V^T dim-row: 32 tokens + 8 pad (bank decorrelation)
#define P_STRIDE  40   // shorts per P qrow

__device__ __forceinline__ short f2bf(float f) {
    union { float f; uint32_t u; } v; v.f = f;
    uint32_t r = (v.u + 0x7FFFu + ((v.u >> 16) & 1u)) >> 16;  // RNE
    return (short)r;
}

__device__ __forceinline__ s16x8 cvt8(f32x4 a, f32x4 b) {
    s16x8 r;
    r[0] = f2bf(a[0]); r[1] = f2bf(a[1]); r[2] = f2bf(a[2]); r[3] = f2bf(a[3]);
    r[4] = f2bf(b[0]); r[5] = f2bf(b[1]); r[6] = f2bf(b[2]); r[7] = f2bf(b[3]);
    return r;
}

// grid: 256 blocks = (seq, kv_head); 256 threads = 4 waves; wave w owns tokens [w*512, w*512+512)
__global__ __launch_bounds__(256, 1) void mla_decode(
    const float* __restrict__ qn, const float* __restrict__ qr,
    const float* __restrict__ kn, const float* __restrict__ kr,
    const int* __restrict__ bt, float* __restrict__ out)
{
    // LDS: [0,40960): V^T per wave (128 dims x 40 shorts); [40960,51200): P per wave (32 x 40 shorts)
    // combine phase reuses [0, 33280) as two fp32 slots of 4160 floats each
    __shared__ __align__(16) char smem[51200];

    const int tid = threadIdx.x;
    const int w   = tid >> 6;
    const int l   = tid & 63;
    const int s   = blockIdx.x >> 2;
    const int h   = blockIdx.x & 3;
    const int l15 = l & 15;
    const int l4  = l >> 4;

    short* Vt = (short*)smem + w * (DN * VT_STRIDE);
    short* Pl = (short*)(smem + 4 * DN * VT_STRIDE * 2) + w * (32 * P_STRIDE);

    // ---- Q fragments (B-layout, resident all kernel): qf[ks][nt]
    // qcol = qpos*8 + g; B-frag: n = l&15 (+16*nt), k = (l>>4)*8 + j (+32*ks)
    s16x8 qf[6][2];
    #pragma unroll
    for (int nt = 0; nt < 2; ++nt) {
        int qcol = l15 + 16 * nt;
        int qpos = qcol >> 3, g = qcol & 7;
        const float* qnb = qn + ((size_t)((s*QL + qpos)*NH + h*GRP + g)) * DN + l4*8;
        const float* qrb = qr + ((size_t)((s*QL + qpos)*NH + h*GRP + g)) * DR + l4*8;
        #pragma unroll
        for (int ks = 0; ks < 4; ++ks) {
            f32x4 a = *(const f32x4*)(qnb + 32*ks);
            f32x4 b = *(const f32x4*)(qnb + 32*ks + 4);
            qf[ks][nt] = cvt8(a, b);
        }
        #pragma unroll
        for (int ks = 0; ks < 2; ++ks) {
            f32x4 a = *(const f32x4*)(qrb + 32*ks);
            f32x4 b = *(const f32x4*)(qrb + 32*ks + 4);
            qf[4+ks][nt] = cvt8(a, b);
        }
    }

    const float scale = 0.07216878364870322f;  // 1/sqrt(192)

    f32x4 of[8][2];                    // O^T accum: row dim=16mt+(l>>4)*4+r, col qcol=(l&15)+16nt
    #pragma unroll
    for (int mt = 0; mt < 8; ++mt)
        #pragma unroll
        for (int nt = 0; nt < 2; ++nt) of[mt][nt] = f32x4{0.f, 0.f, 0.f, 0.f};
    float m2[2] = {-INFINITY, -INFINITY};
    float l2[2] = {0.f, 0.f};

    const int btbase = s * (KL / BS) + w * 32;

    #pragma unroll 1
    for (int c = 0; c < 16; ++c) {   // 16 chunks x 32 tokens per wave
        f32x4 sf[2][2];
        #pragma unroll
        for (int mt = 0; mt < 2; ++mt)
            #pragma unroll
            for (int nt = 0; nt < 2; ++nt) sf[mt][nt] = f32x4{0.f, 0.f, 0.f, 0.f};

        #pragma unroll
        for (int mt = 0; mt < 2; ++mt) {
            int blk = bt[btbase + c*2 + mt];   // one kv-block per 16-token mt tile (uniform)
            const float* knb = kn + ((size_t)(blk*BS + l15)*KVH + h) * DN + l4*8;
            const float* krb = kr + ((size_t)(blk*BS + l15)*KVH + h) * DR + l4*8;
            f32x4 ld[12];
            #pragma unroll
            for (int ks = 0; ks < 4; ++ks) {
                ld[2*ks]   = *(const f32x4*)(knb + 32*ks);
                ld[2*ks+1] = *(const f32x4*)(knb + 32*ks + 4);
            }
            #pragma unroll
            for (int ks = 0; ks < 2; ++ks) {
                ld[8+2*ks]   = *(const f32x4*)(krb + 32*ks);
                ld[8+2*ks+1] = *(const f32x4*)(krb + 32*ks + 4);
            }
            s16x8 af[6];
            #pragma unroll
            for (int ks = 0; ks < 6; ++ks) af[ks] = cvt8(ld[2*ks], ld[2*ks+1]);
            // stage V^T (nope dims only) for the PV transpose; same-wave lgkm ordering, no barrier
            #pragma unroll
            for (int ks = 0; ks < 4; ++ks) {
                int dbase = l4*8 + 32*ks;
                #pragma unroll
                for (int j = 0; j < 8; ++j)
                    Vt[(dbase + j) * VT_STRIDE + 16*mt + l15] = af[ks][j];
            }
            // S^T = K * Q^T  (A = K tile: m=token, B = Q: n=qcol)
            #pragma unroll
            for (int ks = 0; ks < 6; ++ks) {
                sf[mt][0] = __builtin_amdgcn_mfma_f32_16x16x32_bf16(af[ks], qf[ks][0], sf[mt][0], 0, 0, 0);
                sf[mt][1] = __builtin_amdgcn_mfma_f32_16x16x32_bf16(af[ks], qf[ks][1], sf[mt][1], 0, 0, 0);
            }
        }

        // ---- online softmax over this chunk's 32 tokens (token dim = regs + lane>>4 groups)
        float cmax[2] = {-INFINITY, -INFINITY};
        #pragma unroll
        for (int mt = 0; mt < 2; ++mt)
            #pragma unroll
            for (int nt = 0; nt < 2; ++nt)
                #pragma unroll
                for (int r = 0; r < 4; ++r) cmax[nt] = fmaxf(cmax[nt], sf[mt][nt][r]);
        #pragma unroll
        for (int nt = 0; nt < 2; ++nt) {
            cmax[nt] = fmaxf(cmax[nt], __shfl_xor(cmax[nt], 16, 64));
            cmax[nt] = fmaxf(cmax[nt], __shfl_xor(cmax[nt], 32, 64));
        }
        float alpha[2], psum[2];
        #pragma unroll
        for (int nt = 0; nt < 2; ++nt) {
            float mn = fmaxf(m2[nt], cmax[nt] * scale);
            alpha[nt] = __expf(m2[nt] - mn);
            m2[nt] = mn;
            psum[nt] = 0.f;
        }
        float p[2][2][4];
        #pragma unroll
        for (int mt = 0; mt < 2; ++mt)
            #pragma unroll
            for (int nt = 0; nt < 2; ++nt)
                #pragma unroll
                for (int r = 0; r < 4; ++r) {
                    float e = __expf(sf[mt][nt][r] * scale - m2[nt]);
                    p[mt][nt][r] = e; psum[nt] += e;
                }
        #pragma unroll
        for (int nt = 0; nt < 2; ++nt) {
            psum[nt] += __shfl_xor(psum[nt], 16, 64);
            psum[nt] += __shfl_xor(psum[nt], 32, 64);
            l2[nt] = l2[nt] * alpha[nt] + psum[nt];
        }
        #pragma unroll
        for (int mt = 0; mt < 8; ++mt)
            #pragma unroll
            for (int nt = 0; nt < 2; ++nt) {
                of[mt][nt][0] *= alpha[nt]; of[mt][nt][1] *= alpha[nt];
                of[mt][nt][2] *= alpha[nt]; of[mt][nt][3] *= alpha[nt];
            }

        // ---- P round-trip: C-layout (4 consecutive tokens per lane) -> b64 write; B-frag b128 read
        #pragma unroll
        for (int mt = 0; mt < 2; ++mt)
            #pragma unroll
            for (int nt = 0; nt < 2; ++nt) {
                unsigned lo = (unsigned short)f2bf(p[mt][nt][0]) | ((unsigned)(unsigned short)f2bf(p[mt][nt][1]) << 16);
                unsigned hi = (unsigned short)f2bf(p[mt][nt][2]) | ((unsigned)(unsigned short)f2bf(p[mt][nt][3]) << 16);
                unsigned long long v = (unsigned long long)lo | ((unsigned long long)hi << 32);
                *(unsigned long long*)(Pl + (l15 + 16*nt) * P_STRIDE + 16*mt + l4*4) = v;
            }
        s16x8 pf[2];
        #pragma unroll
        for (int nt = 0; nt < 2; ++nt)
            pf[nt] = *(const s16x8*)(Pl + (l15 + 16*nt) * P_STRIDE + l4*8);

        // ---- O^T += V^T * P^T  (A = V^T: m=dim, k=token; B = P^T: n=qcol, k=token)
        #pragma unroll
        for (int mt = 0; mt < 8; ++mt) {
            s16x8 vf = *(const s16x8*)(Vt + (l15 + 16*mt) * VT_STRIDE + l4*8);
            of[mt][0] = __builtin_amdgcn_mfma_f32_16x16x32_bf16(vf, pf[0], of[mt][0], 0, 0, 0);
            of[mt][1] = __builtin_amdgcn_mfma_f32_16x16x32_bf16(vf, pf[1], of[mt][1], 0, 0, 0);
        }
    }

    // ---- cross-wave flash combine (tree, 2 fp32 LDS slots, reuses main-loop LDS)
    auto dump = [&](int slot) {
        float* sp = (float*)smem + slot * 4160;
        #pragma unroll
        for (int mt = 0; mt < 8; ++mt)
            #pragma unroll
            for (int nt = 0; nt < 2; ++nt)
                #pragma unroll
                for (int r = 0; r < 4; ++r)
                    sp[(16*mt + l4*4 + r) * 32 + l15 + 16*nt] = of[mt][nt][r];
        if (l4 == 0) {
            sp[4096 + l15]      = m2[0]; sp[4096 + 16 + l15] = m2[1];
            sp[4128 + l15]      = l2[0]; sp[4128 + 16 + l15] = l2[1];
        }
    };
    auto merge = [&](int slot) {
        float* sp = (float*)smem + slot * 4160;
        float as[2], ao[2];
        #pragma unroll
        for (int nt = 0; nt < 2; ++nt) {
            int qcol = l15 + 16*nt;
            float mo = sp[4096 + qcol];
            float lo = sp[4128 + qcol];
            float mn = fmaxf(m2[nt], mo);
            as[nt] = __expf(m2[nt] - mn);
            ao[nt] = __expf(mo - mn);
            l2[nt] = l2[nt] * as[nt] + lo * ao[nt];
            m2[nt] = mn;
        }
        #pragma unroll
        for (int mt = 0; mt < 8; ++mt)
            #pragma unroll
            for (int nt = 0; nt < 2; ++nt)
                #pragma unroll
                for (int r = 0; r < 4; ++r)
                    of[mt][nt][r] = of[mt][nt][r] * as[nt]
                                  + sp[(16*mt + l4*4 + r) * 32 + l15 + 16*nt] * ao[nt];
    };

    __syncthreads();
    if (w & 1) dump(w >> 1);          // waves 1,3 -> slots 0,1
    __syncthreads();
    if (!(w & 1)) merge(w >> 1);      // waves 0,2 merge partners
    __syncthreads();
    if (w == 2) dump(0);
    __syncthreads();
    if (w == 0) {
        merge(0);
        float inv[2] = {1.f / l2[0], 1.f / l2[1]};
        #pragma unroll
        for (int nt = 0; nt < 2; ++nt) {
            int qcol = l15 + 16*nt;
            int qpos = qcol >> 3, g = qcol & 7;
            float* ob = out + ((size_t)((s*QL + qpos)*NH + h*GRP + g)) * DN;
            #pragma unroll
            for (int mt = 0; mt < 8; ++mt) {
                f32x4 v;
                v[0] = of[mt][nt][0] * inv[nt]; v[1] = of[mt][nt][1] * inv[nt];
                v[2] = of[mt][nt][2] * inv[nt]; v[3] = of[mt][nt][3] * inv[nt];
                *(f32x4*)(ob + 16*mt + l4*4) = v;
            }
        }
    }
}

extern "C" void kernel_launch(void* const* d_in, const int* in_sizes, int n_in,
                              void* d_out, int out_size, void* d_ws, size_t ws_size,
                              hipStream_t stream) {
    (void)in_sizes; (void)n_in; (void)out_size; (void)d_ws; (void)ws_size;
    const float* qn = (const float*)d_in[0];
    const float* qr = (const float*)d_in[1];
    const float* kn = (const float*)d_in[2];
    const float* kr = (const float*)d_in[3];
    const int*   bt = (const int*)d_in[4];
    float* out = (float*)d_out;
    mla_decode<<<SEQS * KVH, 256, 0, stream>>>(qn, qr, kn, kr, bt, out);
}

// Round 2
// 429.534 us; speedup vs baseline: 1.0127x; 1.0127x over previous
//
#include <hip/hip_runtime.h>
#include <stdint.h>

#define SEQS 64
#define QL 4
#define KL 2048
#define NH 32
#define KVH 4
#define GRP 8
#define DN 128
#define DR 64
#define BS 16

typedef __attribute__((ext_vector_type(4))) float f32x4;
typedef __attribute__((ext_vector_type(8))) short s16x8;

#define VT_STRIDE 40   // shorts per V^T dim-row: 32 tokens + 8 pad (bank decorrelation)
#define P_STRIDE  40   // shorts per P qrow

__device__ __forceinline__ short f2bf(float f) {
    union { float f; uint32_t u; } v; v.f = f;
    uint32_t r = (v.u + 0x7FFFu + ((v.u >> 16) & 1u)) >> 16;  // RNE
    return (short)r;
}

__device__ __forceinline__ s16x8 cvt8(f32x4 a, f32x4 b) {
    s16x8 r;
    r[0] = f2bf(a[0]); r[1] = f2bf(a[1]); r[2] = f2bf(a[2]); r[3] = f2bf(a[3]);
    r[4] = f2bf(b[0]); r[5] = f2bf(b[1]); r[6] = f2bf(b[2]); r[7] = f2bf(b[3]);
    return r;
}

// grid: 256 blocks = (seq, kv_head); 256 threads = 4 waves; wave w owns tokens [w*512, w*512+512)
// Pipeline: per 16-token tile, 12 float4 K/V loads are register-double-buffered one tile ahead,
// so 12-24 loads/wave stay in flight through cvt/MFMA/softmax (latency → BW bound).
__global__ __launch_bounds__(256, 1) void mla_decode(
    const float* __restrict__ qn, const float* __restrict__ qr,
    const float* __restrict__ kn, const float* __restrict__ kr,
    const int* __restrict__ bt, float* __restrict__ out)
{
    // LDS: [0,40960): V^T per wave (128 dims x 40 shorts); [40960,51200): P per wave (32 x 40 shorts)
    // combine phase reuses [0, 33280) as two fp32 slots of 4160 floats each
    __shared__ __align__(16) char smem[51200];

    const int tid = threadIdx.x;
    const int w   = tid >> 6;
    const int l   = tid & 63;
    const int s   = blockIdx.x >> 2;
    const int h   = blockIdx.x & 3;
    const int l15 = l & 15;
    const int l4  = l >> 4;

    short* Vt = (short*)smem + w * (DN * VT_STRIDE);
    short* Pl = (short*)(smem + 4 * DN * VT_STRIDE * 2) + w * (32 * P_STRIDE);

    // ---- Q fragments (B-layout, resident all kernel): qf[ks][nt]
    s16x8 qf[6][2];
    #pragma unroll
    for (int nt = 0; nt < 2; ++nt) {
        int qcol = l15 + 16 * nt;
        int qpos = qcol >> 3, g = qcol & 7;
        const float* qnb = qn + ((size_t)((s*QL + qpos)*NH + h*GRP + g)) * DN + l4*8;
        const float* qrb = qr + ((size_t)((s*QL + qpos)*NH + h*GRP + g)) * DR + l4*8;
        #pragma unroll
        for (int ks = 0; ks < 4; ++ks) {
            f32x4 a = *(const f32x4*)(qnb + 32*ks);
            f32x4 b = *(const f32x4*)(qnb + 32*ks + 4);
            qf[ks][nt] = cvt8(a, b);
        }
        #pragma unroll
        for (int ks = 0; ks < 2; ++ks) {
            f32x4 a = *(const f32x4*)(qrb + 32*ks);
            f32x4 b = *(const f32x4*)(qrb + 32*ks + 4);
            qf[4+ks][nt] = cvt8(a, b);
        }
    }

    const float scale = 0.07216878364870322f;  // 1/sqrt(192)

    f32x4 of[8][2];                    // O^T accum: row dim=16mt+(l>>4)*4+r, col qcol=(l&15)+16nt
    #pragma unroll
    for (int mt = 0; mt < 8; ++mt)
        #pragma unroll
        for (int nt = 0; nt < 2; ++nt) of[mt][nt] = f32x4{0.f, 0.f, 0.f, 0.f};
    float m2[2] = {-INFINITY, -INFINITY};
    float l2[2] = {0.f, 0.f};

    const int btbase = s * (KL / BS) + w * 32;
    // all 32 block ids for this wave, lane-indexed (lanes 32-63 duplicate): kills per-chunk bt stall
    const int btreg = bt[btbase + (l & 31)];

    // issue the 12 float4 loads (one 16-token kv-block: 128 nope + 64 rope dims) for block id blkv
    auto loadK = [&](int blkv, f32x4* dst) {
        int blk = __builtin_amdgcn_readfirstlane(blkv);   // scalar base -> SALU addressing
        const float* knb = kn + ((size_t)(blk*BS + l15)*KVH + h) * DN + l4*8;
        const float* krb = kr + ((size_t)(blk*BS + l15)*KVH + h) * DR + l4*8;
        #pragma unroll
        for (int ks = 0; ks < 4; ++ks) {
            dst[2*ks]   = *(const f32x4*)(knb + 32*ks);
            dst[2*ks+1] = *(const f32x4*)(knb + 32*ks + 4);
        }
        #pragma unroll
        for (int ks = 0; ks < 2; ++ks) {
            dst[8+2*ks]   = *(const f32x4*)(krb + 32*ks);
            dst[8+2*ks+1] = *(const f32x4*)(krb + 32*ks + 4);
        }
    };

    f32x4 buf0[12], buf1[12];
    loadK(__shfl(btreg, 0, 64), buf0);

    #pragma unroll 1
    for (int c = 0; c < 16; ++c) {   // 16 chunks x 32 tokens per wave
        f32x4 sf[2][2];
        #pragma unroll
        for (int mt = 0; mt < 2; ++mt)
            #pragma unroll
            for (int nt = 0; nt < 2; ++nt) sf[mt][nt] = f32x4{0.f, 0.f, 0.f, 0.f};

        auto qkstep = [&](const f32x4* ld, int mt) {
            s16x8 af[6];
            #pragma unroll
            for (int ks = 0; ks < 6; ++ks) af[ks] = cvt8(ld[2*ks], ld[2*ks+1]);
            // stage V^T (nope dims only); same-wave lgkm ordering, no barrier
            #pragma unroll
            for (int ks = 0; ks < 4; ++ks) {
                int dbase = l4*8 + 32*ks;
                #pragma unroll
                for (int j = 0; j < 8; ++j)
                    Vt[(dbase + j) * VT_STRIDE + 16*mt + l15] = af[ks][j];
            }
            // S^T = K * Q^T  (A = K tile: m=token, B = Q: n=qcol)
            #pragma unroll
            for (int ks = 0; ks < 6; ++ks) {
                sf[mt][0] = __builtin_amdgcn_mfma_f32_16x16x32_bf16(af[ks], qf[ks][0], sf[mt][0], 0, 0, 0);
                sf[mt][1] = __builtin_amdgcn_mfma_f32_16x16x32_bf16(af[ks], qf[ks][1], sf[mt][1], 0, 0, 0);
            }
        };

        loadK(__shfl(btreg, 2*c + 1, 64), buf1);      // prefetch tile (c, mt=1)
        qkstep(buf0, 0);
        if (c + 1 < 16)
            loadK(__shfl(btreg, 2*c + 2, 64), buf0);  // prefetch tile (c+1, mt=0)
        qkstep(buf1, 1);

        // ---- online softmax over this chunk's 32 tokens
        float cmax[2] = {-INFINITY, -INFINITY};
        #pragma unroll
        for (int mt = 0; mt < 2; ++mt)
            #pragma unroll
            for (int nt = 0; nt < 2; ++nt)
                #pragma unroll
                for (int r = 0; r < 4; ++r) cmax[nt] = fmaxf(cmax[nt], sf[mt][nt][r]);
        #pragma unroll
        for (int nt = 0; nt < 2; ++nt) {
            cmax[nt] = fmaxf(cmax[nt], __shfl_xor(cmax[nt], 16, 64));
            cmax[nt] = fmaxf(cmax[nt], __shfl_xor(cmax[nt], 32, 64));
        }
        float alpha[2], psum[2];
        #pragma unroll
        for (int nt = 0; nt < 2; ++nt) {
            float mn = fmaxf(m2[nt], cmax[nt] * scale);
            alpha[nt] = __expf(m2[nt] - mn);
            m2[nt] = mn;
            psum[nt] = 0.f;
        }
        float p[2][2][4];
        #pragma unroll
        for (int mt = 0; mt < 2; ++mt)
            #pragma unroll
            for (int nt = 0; nt < 2; ++nt)
                #pragma unroll
                for (int r = 0; r < 4; ++r) {
                    float e = __expf(sf[mt][nt][r] * scale - m2[nt]);
                    p[mt][nt][r] = e; psum[nt] += e;
                }
        #pragma unroll
        for (int nt = 0; nt < 2; ++nt) {
            psum[nt] += __shfl_xor(psum[nt], 16, 64);
            psum[nt] += __shfl_xor(psum[nt], 32, 64);
            l2[nt] = l2[nt] * alpha[nt] + psum[nt];
        }
        #pragma unroll
        for (int mt = 0; mt < 8; ++mt)
            #pragma unroll
            for (int nt = 0; nt < 2; ++nt) {
                of[mt][nt][0] *= alpha[nt]; of[mt][nt][1] *= alpha[nt];
                of[mt][nt][2] *= alpha[nt]; of[mt][nt][3] *= alpha[nt];
            }

        // ---- P round-trip: C-layout -> b64 write; B-frag b128 read
        #pragma unroll
        for (int mt = 0; mt < 2; ++mt)
            #pragma unroll
            for (int nt = 0; nt < 2; ++nt) {
                unsigned lo = (unsigned short)f2bf(p[mt][nt][0]) | ((unsigned)(unsigned short)f2bf(p[mt][nt][1]) << 16);
                unsigned hi = (unsigned short)f2bf(p[mt][nt][2]) | ((unsigned)(unsigned short)f2bf(p[mt][nt][3]) << 16);
                unsigned long long v = (unsigned long long)lo | ((unsigned long long)hi << 32);
                *(unsigned long long*)(Pl + (l15 + 16*nt) * P_STRIDE + 16*mt + l4*4) = v;
            }
        s16x8 pf[2];
        #pragma unroll
        for (int nt = 0; nt < 2; ++nt)
            pf[nt] = *(const s16x8*)(Pl + (l15 + 16*nt) * P_STRIDE + l4*8);

        // ---- O^T += V^T * P^T
        #pragma unroll
        for (int mt = 0; mt < 8; ++mt) {
            s16x8 vf = *(const s16x8*)(Vt + (l15 + 16*mt) * VT_STRIDE + l4*8);
            of[mt][0] = __builtin_amdgcn_mfma_f32_16x16x32_bf16(vf, pf[0], of[mt][0], 0, 0, 0);
            of[mt][1] = __builtin_amdgcn_mfma_f32_16x16x32_bf16(vf, pf[1], of[mt][1], 0, 0, 0);
        }
    }

    // ---- cross-wave flash combine (tree, 2 fp32 LDS slots, reuses main-loop LDS)
    auto dump = [&](int slot) {
        float* sp = (float*)smem + slot * 4160;
        #pragma unroll
        for (int mt = 0; mt < 8; ++mt)
            #pragma unroll
            for (int nt = 0; nt < 2; ++nt)
                #pragma unroll
                for (int r = 0; r < 4; ++r)
                    sp[(16*mt + l4*4 + r) * 32 + l15 + 16*nt] = of[mt][nt][r];
        if (l4 == 0) {
            sp[4096 + l15]      = m2[0]; sp[4096 + 16 + l15] = m2[1];
            sp[4128 + l15]      = l2[0]; sp[4128 + 16 + l15] = l2[1];
        }
    };
    auto merge = [&](int slot) {
        float* sp = (float*)smem + slot * 4160;
        float as[2], ao[2];
        #pragma unroll
        for (int nt = 0; nt < 2; ++nt) {
            int qcol = l15 + 16*nt;
            float mo = sp[4096 + qcol];
            float lo = sp[4128 + qcol];
            float mn = fmaxf(m2[nt], mo);
            as[nt] = __expf(m2[nt] - mn);
            ao[nt] = __expf(mo - mn);
            l2[nt] = l2[nt] * as[nt] + lo * ao[nt];
            m2[nt] = mn;
        }
        #pragma unroll
        for (int mt = 0; mt < 8; ++mt)
            #pragma unroll
            for (int nt = 0; nt < 2; ++nt)
                #pragma unroll
                for (int r = 0; r < 4; ++r)
                    of[mt][nt][r] = of[mt][nt][r] * as[nt]
                                  + sp[(16*mt + l4*4 + r) * 32 + l15 + 16*nt] * ao[nt];
    };

    __syncthreads();
    if (w & 1) dump(w >> 1);          // waves 1,3 -> slots 0,1
    __syncthreads();
    if (!(w & 1)) merge(w >> 1);      // waves 0,2 merge partners
    __syncthreads();
    if (w == 2) dump(0);
    __syncthreads();
    if (w == 0) {
        merge(0);
        float inv[2] = {1.f / l2[0], 1.f / l2[1]};
        #pragma unroll
        for (int nt = 0; nt < 2; ++nt) {
            int qcol = l15 + 16*nt;
            int qpos = qcol >> 3, g = qcol & 7;
            float* ob = out + ((size_t)((s*QL + qpos)*NH + h*GRP + g)) * DN;
            #pragma unroll
            for (int mt = 0; mt < 8; ++mt) {
                f32x4 v;
                v[0] = of[mt][nt][0] * inv[nt]; v[1] = of[mt][nt][1] * inv[nt];
                v[2] = of[mt][nt][2] * inv[nt]; v[3] = of[mt][nt][3] * inv[nt];
                *(f32x4*)(ob + 16*mt + l4*4) = v;
            }
        }
    }
}

extern "C" void kernel_launch(void* const* d_in, const int* in_sizes, int n_in,
                              void* d_out, int out_size, void* d_ws, size_t ws_size,
                              hipStream_t stream) {
    (void)in_sizes; (void)n_in; (void)out_size; (void)d_ws; (void)ws_size;
    const float* qn = (const float*)d_in[0];
    const float* qr = (const float*)d_in[1];
    const float* kn = (const float*)d_in[2];
    const float* kr = (const float*)d_in[3];
    const int*   bt = (const int*)d_in[4];
    float* out = (float*)d_out;
    mla_decode<<<SEQS * KVH, 256, 0, stream>>>(qn, qr, kn, kr, bt, out);
}